// Round 4
// baseline (64.996 us; speedup 1.0000x reference)
//
#include <hip/hip_runtime.h>
#include <math.h>

#define TJ 32

// Kernel 1: a[b,p] = sum_c |in[b,p,c]|, stored transposed Ft[p*8+b];
// per-block min/max partials; zero the output scalar.
__global__ __launch_bounds__(256) void prep_kernel(const float* __restrict__ in,
                                                   float* __restrict__ Ft,
                                                   float* __restrict__ bmin,
                                                   float* __restrict__ bmax,
                                                   float* __restrict__ out) {
    const int t = threadIdx.x;
    const int g = blockIdx.x * 256 + t;      // 0..32767
    const int b = g >> 12;                   // batch 0..7
    const int p = g & 4095;                  // pixel 0..4095
    const float* s = in + b * 12288 + p * 3;
    const float v = fabsf(s[0]) + fabsf(s[1]) + fabsf(s[2]);
    Ft[p * 8 + b] = v;

    float mn = v, mx = v;
    #pragma unroll
    for (int off = 32; off > 0; off >>= 1) {
        mn = fminf(mn, __shfl_down(mn, off));
        mx = fmaxf(mx, __shfl_down(mx, off));
    }
    __shared__ float smn[4], smx[4];
    if ((t & 63) == 0) { smn[t >> 6] = mn; smx[t >> 6] = mx; }
    __syncthreads();
    if (t == 0) {
        mn = fminf(fminf(smn[0], smn[1]), fminf(smn[2], smn[3]));
        mx = fmaxf(fmaxf(smx[0], smx[1]), fmaxf(smx[2], smx[3]));
        bmin[blockIdx.x] = mn;
        bmax[blockIdx.x] = mx;
        if (blockIdx.x == 0) out[0] = 0.0f;   // d_out is poisoned 0xAA each replay
    }
}

// Kernel 2: triangular tile grid (R3) + two register-level levers:
//  (a) per-thread distance table: dc = dc0 + m - jj takes only 35 distinct
//      values across the 128 (m,jj) pairs -> 35 sqrts instead of 128, fully
//      unrolled loop so dtab[jj-m+3] is a compile-time register index;
//  (b) wave-level diagonal clipping: all surviving pairs are weight-2 (j>i;
//      j==i has d=0), folded into the final /2^26. Per wave a j-tile is
//      fully-below (skip loop), fully-above (plain table), or wave-diagonal
//      (zero table entries with k <= cthr once, 35 cndmasks).
__global__ __launch_bounds__(256) void pair_kernel(const float* __restrict__ Ft,
                                                   const float* __restrict__ bmin,
                                                   const float* __restrict__ bmax,
                                                   float* __restrict__ out) {
    const int t = threadIdx.x;
    // decode triangular block id -> (x, by);  by >= 32x
    const int k = blockIdx.x;
    int x, by;
    if (k < 128)      { x = 0; by = k; }
    else if (k < 224) { x = 1; by = k - 128 + 32; }
    else if (k < 288) { x = 2; by = k - 224 + 64; }
    else              { x = 3; by = k - 288 + 96; }

    __shared__ float s_mn, s_sc;
    __shared__ __align__(16) float vjs[TJ * 8];

    // reduce the 128 per-block min/max partials (wave 0 only)
    if (t < 64) {
        float mn = fminf(bmin[t], bmin[t + 64]);
        float mx = fmaxf(bmax[t], bmax[t + 64]);
        #pragma unroll
        for (int off = 32; off > 0; off >>= 1) {
            mn = fminf(mn, __shfl_down(mn, off));
            mx = fmaxf(mx, __shfl_down(mx, off));
        }
        if (t == 0) { s_mn = mn; s_sc = 1.0f / (mx - mn); }
    }
    __syncthreads();
    const float mn = s_mn, sc = s_sc;

    // stage normalized j-tile: TJ*8 = 256 floats, one per thread (coalesced)
    const int j0 = by * TJ;
    vjs[t] = (Ft[j0 * 8 + t] - mn) * sc;

    // load + normalize this thread's 4 V_i vectors (128B contiguous per lane)
    const int ibase = x * 1024 + t * 4;
    float vi[4][8];
    const float4* fv = (const float4*)(Ft + (size_t)ibase * 8);
    #pragma unroll
    for (int m = 0; m < 4; ++m) {
        float4 q0 = fv[m * 2 + 0];
        float4 q1 = fv[m * 2 + 1];
        vi[m][0] = (q0.x - mn) * sc; vi[m][1] = (q0.y - mn) * sc;
        vi[m][2] = (q0.z - mn) * sc; vi[m][3] = (q0.w - mn) * sc;
        vi[m][4] = (q1.x - mn) * sc; vi[m][5] = (q1.y - mn) * sc;
        vi[m][6] = (q1.z - mn) * sc; vi[m][7] = (q1.w - mn) * sc;
    }
    __syncthreads();

    // geometry: all 4 i's share one grid row; all TJ j's share one row.
    const float fri = (float)(ibase >> 6);
    const float frj = (float)(j0 >> 6);
    const float fdr = fri - frj;
    const float r2 = fdr * fdr;                       // tile-constant
    const float dc0 = (float)(ibase & 63) - (float)(j0 & 63);

    // distance table: k = jj - m + 3  ->  dc = dc0 + m - jj = dc0 + 3 - k
    float dtab[35];
    #pragma unroll
    for (int kk = 0; kk < 35; ++kk) {
        const float dc = dc0 + 3.0f - (float)kk;
        dtab[kk] = __builtin_amdgcn_sqrtf(fmaf(dc, dc, r2));
    }

    // wave mode vs this j-tile (wave-uniform): i-range [wavebase, wavebase+256)
    const int wavebase = x * 1024 + (t >> 6) * 256;
    const bool skip  = (j0 + TJ <= wavebase);         // all j < i
    const bool mixed = !skip && (j0 < wavebase + 256);
    if (mixed) {
        // keep only pairs with j > i:  jj - m > ibase - j0  <=>  k > cthr
        const int cthr = ibase - j0 + 3;
        #pragma unroll
        for (int kk = 0; kk < 35; ++kk)
            dtab[kk] = (kk > cthr) ? dtab[kk] : 0.0f;
    }

    float acc[4] = {0.f, 0.f, 0.f, 0.f};
    if (!skip) {
        #pragma unroll
        for (int jj = 0; jj < TJ; ++jj) {
            const float4* vp = (const float4*)&vjs[jj * 8];
            const float4 a = vp[0];          // uniform LDS addr -> broadcast
            const float4 c = vp[1];
            #pragma unroll
            for (int m = 0; m < 4; ++m) {
                const float d = dtab[jj - m + 3];   // compile-time index
                float dot = vi[m][0] * a.x;
                dot = fmaf(vi[m][1], a.y, dot);
                dot = fmaf(vi[m][2], a.z, dot);
                dot = fmaf(vi[m][3], a.w, dot);
                dot = fmaf(vi[m][4], c.x, dot);
                dot = fmaf(vi[m][5], c.y, dot);
                dot = fmaf(vi[m][6], c.z, dot);
                dot = fmaf(vi[m][7], c.w, dot);
                acc[m] = fmaf(d, dot, acc[m]);
            }
        }
    }

    float r = (acc[0] + acc[1]) + (acc[2] + acc[3]);
    #pragma unroll
    for (int off = 32; off > 0; off >>= 1) r += __shfl_down(r, off);
    __shared__ float sacc[4];
    if ((t & 63) == 0) sacc[t >> 6] = r;
    __syncthreads();
    if (t == 0) {
        const float tot = (sacc[0] + sacc[1]) + (sacc[2] + sacc[3]);
        // every surviving pair is the j>i member: weight 2 folded in -> /2^26
        atomicAdd(out, tot * (1.0f / 67108864.0f));
    }
}

extern "C" void kernel_launch(void* const* d_in, const int* in_sizes, int n_in,
                              void* d_out, int out_size, void* d_ws, size_t ws_size,
                              hipStream_t stream) {
    const float* in = (const float*)d_in[0];
    float* out = (float*)d_out;
    float* Ft   = (float*)d_ws;          // 32768 floats (128 KiB)
    float* bmin = Ft + 32768;            // 128 floats
    float* bmax = bmin + 128;            // 128 floats
    prep_kernel<<<dim3(128), dim3(256), 0, stream>>>(in, Ft, bmin, bmax, out);
    pair_kernel<<<dim3(320), dim3(256), 0, stream>>>(Ft, bmin, bmax, out);
    (void)in_sizes; (void)n_in; (void)out_size; (void)ws_size;
}

// Round 5
// 63.351 us; speedup vs baseline: 1.0260x; 1.0260x over previous
//
#include <hip/hip_runtime.h>
#include <math.h>

#define TJ 32

// Kernel 1: a[b,p] = sum_c |in[b,p,c]|, stored transposed Ft[p*8+b];
// per-block min/max partials; zero the output scalar.
__global__ __launch_bounds__(256) void prep_kernel(const float* __restrict__ in,
                                                   float* __restrict__ Ft,
                                                   float* __restrict__ bmin,
                                                   float* __restrict__ bmax,
                                                   float* __restrict__ out) {
    const int t = threadIdx.x;
    const int g = blockIdx.x * 256 + t;      // 0..32767
    const int b = g >> 12;                   // batch 0..7
    const int p = g & 4095;                  // pixel 0..4095
    const float* s = in + b * 12288 + p * 3;
    const float v = fabsf(s[0]) + fabsf(s[1]) + fabsf(s[2]);
    Ft[p * 8 + b] = v;

    float mn = v, mx = v;
    #pragma unroll
    for (int off = 32; off > 0; off >>= 1) {
        mn = fminf(mn, __shfl_down(mn, off));
        mx = fmaxf(mx, __shfl_down(mx, off));
    }
    __shared__ float smn[4], smx[4];
    if ((t & 63) == 0) { smn[t >> 6] = mn; smx[t >> 6] = mx; }
    __syncthreads();
    if (t == 0) {
        mn = fminf(fminf(smn[0], smn[1]), fminf(smn[2], smn[3]));
        mx = fmaxf(fmaxf(smx[0], smx[1]), fmaxf(smx[2], smx[3]));
        bmin[blockIdx.x] = mn;
        bmax[blockIdx.x] = mx;
        if (blockIdx.x == 0) out[0] = 0.0f;   // d_out is poisoned 0xAA each replay
    }
}

// Kernel 2: sum over pairs, TRIANGULAR tile grid exploiting d/g symmetry.
// i-tiles of 1024 (x=0..3), j-tiles of TJ=32 (by=0..127). Block (x,by) exists
// only for by >= 32x: the 32 j-tiles inside the i-tile's own span form the
// fully-symmetric diagonal sub-block (weight 1, computed whole); j-tiles
// strictly beyond it are each the (i<j) member of a mirrored pair (weight 2);
// by < 32x dropped. 320 blocks instead of 512 (-37.5% work), identical inner
// loop. Each thread owns 4 consecutive i's (one grid row); the whole j-tile
// lies in one row too (32 | 64), so dr^2 is a per-thread constant and column
// deltas are maintained by -1.0 decrements. sqrt = raw v_sqrt_f32.
// (R4's dtab[35] full-unroll variant regressed: VGPR pressure cost more than
// the saved sqrts in this latency-bound regime -- reverted.)
__global__ __launch_bounds__(256) void pair_kernel(const float* __restrict__ Ft,
                                                   const float* __restrict__ bmin,
                                                   const float* __restrict__ bmax,
                                                   float* __restrict__ out) {
    const int t = threadIdx.x;
    // decode triangular block id -> (x, by)
    const int k = blockIdx.x;
    int x, by;
    if (k < 128)      { x = 0; by = k; }
    else if (k < 224) { x = 1; by = k - 128 + 32; }
    else if (k < 288) { x = 2; by = k - 224 + 64; }
    else              { x = 3; by = k - 288 + 96; }
    const float wgt = (by >= x * 32 + 32) ? 2.0f : 1.0f;

    __shared__ float s_mn, s_sc;
    __shared__ __align__(16) float vjs[TJ * 8];

    // reduce the 128 per-block min/max partials (wave 0 only)
    if (t < 64) {
        float mn = fminf(bmin[t], bmin[t + 64]);
        float mx = fmaxf(bmax[t], bmax[t + 64]);
        #pragma unroll
        for (int off = 32; off > 0; off >>= 1) {
            mn = fminf(mn, __shfl_down(mn, off));
            mx = fmaxf(mx, __shfl_down(mx, off));
        }
        if (t == 0) { s_mn = mn; s_sc = 1.0f / (mx - mn); }
    }
    __syncthreads();
    const float mn = s_mn, sc = s_sc;

    // stage normalized j-tile: TJ*8 = 256 floats, one per thread (coalesced)
    const int j0 = by * TJ;
    vjs[t] = (Ft[j0 * 8 + t] - mn) * sc;

    // load + normalize this thread's 4 V_i vectors (128B contiguous per lane)
    const int ibase = x * 1024 + t * 4;
    float vi[4][8];
    const float4* fv = (const float4*)(Ft + (size_t)ibase * 8);
    #pragma unroll
    for (int m = 0; m < 4; ++m) {
        float4 q0 = fv[m * 2 + 0];
        float4 q1 = fv[m * 2 + 1];
        vi[m][0] = (q0.x - mn) * sc; vi[m][1] = (q0.y - mn) * sc;
        vi[m][2] = (q0.z - mn) * sc; vi[m][3] = (q0.w - mn) * sc;
        vi[m][4] = (q1.x - mn) * sc; vi[m][5] = (q1.y - mn) * sc;
        vi[m][6] = (q1.z - mn) * sc; vi[m][7] = (q1.w - mn) * sc;
    }
    __syncthreads();

    // geometry: all 4 i's share one row; all TJ j's share one row.
    const float fri = (float)(ibase >> 6);
    const float frj = (float)(j0 >> 6);
    const float fdr = fri - frj;
    const float r2 = fdr * fdr;                       // tile-constant
    const float dc0 = (float)(ibase & 63) - (float)(j0 & 63);
    float dcr[4] = {dc0, dc0 + 1.0f, dc0 + 2.0f, dc0 + 3.0f};
    float acc[4] = {0.f, 0.f, 0.f, 0.f};

    #pragma unroll 8
    for (int jj = 0; jj < TJ; ++jj) {
        const float4* vp = (const float4*)&vjs[jj * 8];
        const float4 a = vp[0];              // uniform LDS addr -> broadcast
        const float4 c = vp[1];
        #pragma unroll
        for (int m = 0; m < 4; ++m) {
            const float d = __builtin_amdgcn_sqrtf(fmaf(dcr[m], dcr[m], r2));
            float dot = vi[m][0] * a.x;
            dot = fmaf(vi[m][1], a.y, dot);
            dot = fmaf(vi[m][2], a.z, dot);
            dot = fmaf(vi[m][3], a.w, dot);
            dot = fmaf(vi[m][4], c.x, dot);
            dot = fmaf(vi[m][5], c.y, dot);
            dot = fmaf(vi[m][6], c.z, dot);
            dot = fmaf(vi[m][7], c.w, dot);
            acc[m] = fmaf(d, dot, acc[m]);
            dcr[m] -= 1.0f;
        }
    }

    float r = (acc[0] + acc[1]) + (acc[2] + acc[3]);
    #pragma unroll
    for (int off = 32; off > 0; off >>= 1) r += __shfl_down(r, off);
    __shared__ float sacc[4];
    if ((t & 63) == 0) sacc[t >> 6] = r;
    __syncthreads();
    if (t == 0) {
        const float tot = (sacc[0] + sacc[1]) + (sacc[2] + sacc[3]);
        atomicAdd(out, tot * (wgt / 134217728.0f));   // /(B*N*N) = /2^27
    }
}

extern "C" void kernel_launch(void* const* d_in, const int* in_sizes, int n_in,
                              void* d_out, int out_size, void* d_ws, size_t ws_size,
                              hipStream_t stream) {
    const float* in = (const float*)d_in[0];
    float* out = (float*)d_out;
    float* Ft   = (float*)d_ws;          // 32768 floats (128 KiB)
    float* bmin = Ft + 32768;            // 128 floats
    float* bmax = bmin + 128;            // 128 floats
    prep_kernel<<<dim3(128), dim3(256), 0, stream>>>(in, Ft, bmin, bmax, out);
    pair_kernel<<<dim3(320), dim3(256), 0, stream>>>(Ft, bmin, bmax, out);
    (void)in_sizes; (void)n_in; (void)out_size; (void)ws_size;
}